// Round 1
// baseline (264.266 us; speedup 1.0000x reference)
//
#include <hip/hip_runtime.h>
#include <hip/hip_bf16.h>

typedef __bf16 bf16x8 __attribute__((ext_vector_type(8)));
typedef float  f32x4  __attribute__((ext_vector_type(4)));

#define NPIX  100352   // 32*56*56
#define CIN   256
#define COUT  256
#define BM    128
#define BK    64
#define APAD  8
#define BPAD  8

// ---- prepass: binarize weights, layout [tap][cout][cin] (cin contiguous) ----
__global__ void binw_kernel(const float* __restrict__ w, __bf16* __restrict__ wbt) {
    const int cout = threadIdx.x;          // 0..255
    const int rc   = blockIdx.x;           // tap*256 + cin
    const float v  = w[(size_t)rc * COUT + cout];
    const float s  = (v > 0.f) ? 1.f : ((v < 0.f) ? -1.f : 0.f);
    const int tap = rc >> 8;
    const int cin = rc & 255;
    wbt[((size_t)(tap * COUT + cout)) * CIN + cin] = (__bf16)s;
}

// ---- main: implicit GEMM, 9 shifted taps, bf16 MFMA ----
__global__ __launch_bounds__(512) void conv_kernel(const float* __restrict__ x,
                                                   const __bf16* __restrict__ wbt,
                                                   float* __restrict__ out) {
    __shared__ __bf16 Alds[BM][BK + APAD];     // [pixel][cin-slice]
    __shared__ __bf16 Blds[COUT][BK + BPAD];   // [cout][cin-slice]

    const int tid  = threadIdx.x;
    const int lane = tid & 63;
    const int wave = tid >> 6;               // 0..7
    const int m_base = (wave >> 2) * 64;     // 0 or 64
    const int n_base = (wave & 3) * 64;      // 0,64,128,192
    const int lr = lane & 15;
    const int kb = (lane >> 4) * 8;

    // A-staging assignment: thread -> (pixel row, 16-channel segment)
    const int arow = tid >> 2;               // 0..127
    const int aseg = tid & 3;                // 0..3
    const int p    = blockIdx.x * BM + arow; // global pixel index
    const int rem  = p % 3136;               // within batch image
    const int h    = rem / 56;
    const int wc   = rem % 56;

    f32x4 acc[4][4];
    #pragma unroll
    for (int i = 0; i < 4; ++i)
        #pragma unroll
        for (int j = 0; j < 4; ++j)
            acc[i][j] = (f32x4){0.f, 0.f, 0.f, 0.f};

    for (int tap = 0; tap < 9; ++tap) {
        const int dh = tap / 3 - 1;
        const int dw = tap % 3 - 1;
        const bool valid = ((unsigned)(h + dh) < 56u) && ((unsigned)(wc + dw) < 56u);
        const long aoff = ((long)p + (long)dh * 56 + dw) * CIN + aseg * 16;
        const __bf16* bsrc = wbt + (size_t)tap * COUT * CIN;

        #pragma unroll
        for (int ks = 0; ks < 4; ++ks) {
            const int c0 = ks * BK;
            __syncthreads();   // previous iteration's frag reads done

            // ---- stage A: 128 pixels x 64 cin, fp32 -> bf16 ----
            f32x4 f0, f1, f2, f3;
            if (valid) {
                const f32x4* s4 = (const f32x4*)(x + aoff + c0);
                f0 = s4[0]; f1 = s4[1]; f2 = s4[2]; f3 = s4[3];
            } else {
                f0 = f1 = f2 = f3 = (f32x4){0.f, 0.f, 0.f, 0.f};
            }
            bf16x8 v0, v1;
            #pragma unroll
            for (int j = 0; j < 4; ++j) {
                v0[j]     = (__bf16)f0[j];
                v0[j + 4] = (__bf16)f1[j];
                v1[j]     = (__bf16)f2[j];
                v1[j + 4] = (__bf16)f3[j];
            }
            *(bf16x8*)&Alds[arow][aseg * 16]     = v0;
            *(bf16x8*)&Alds[arow][aseg * 16 + 8] = v1;

            // ---- stage B: 256 couts x 64 cin (already bf16, bit-copy) ----
            #pragma unroll
            for (int i = 0; i < 4; ++i) {
                const int chunk = tid + i * 512;
                const int row = chunk >> 3;       // cout 0..255
                const int cs  = chunk & 7;        // 8-elem chunk
                const uint4 bv = *(const uint4*)(bsrc + row * CIN + c0 + cs * 8);
                *(uint4*)&Blds[row][cs * 8] = bv;
            }
            __syncthreads();

            // ---- fragments ----
            bf16x8 af[4][2], bfr[4][2];
            #pragma unroll
            for (int mf = 0; mf < 4; ++mf)
                #pragma unroll
                for (int kf = 0; kf < 2; ++kf)
                    af[mf][kf] = *(const bf16x8*)&Alds[m_base + mf * 16 + lr][kf * 32 + kb];
            #pragma unroll
            for (int nf = 0; nf < 4; ++nf)
                #pragma unroll
                for (int kf = 0; kf < 2; ++kf)
                    bfr[nf][kf] = *(const bf16x8*)&Blds[n_base + nf * 16 + lr][kf * 32 + kb];

            // ---- MFMA ----
            #pragma unroll
            for (int kf = 0; kf < 2; ++kf)
                #pragma unroll
                for (int mf = 0; mf < 4; ++mf)
                    #pragma unroll
                    for (int nf = 0; nf < 4; ++nf)
                        acc[mf][nf] = __builtin_amdgcn_mfma_f32_16x16x32_bf16(
                            af[mf][kf], bfr[nf][kf], acc[mf][nf], 0, 0, 0);
        }
    }

    // ---- epilogue: C/D map col=lane&15, row=(lane>>4)*4+j (verified m89/m91) ----
    #pragma unroll
    for (int mf = 0; mf < 4; ++mf) {
        #pragma unroll
        for (int nf = 0; nf < 4; ++nf) {
            const int row0 = blockIdx.x * BM + m_base + mf * 16 + (lane >> 4) * 4;
            const int col  = n_base + nf * 16 + lr;
            #pragma unroll
            for (int j = 0; j < 4; ++j)
                out[(size_t)(row0 + j) * COUT + col] = acc[mf][nf][j];
        }
    }
}

extern "C" void kernel_launch(void* const* d_in, const int* in_sizes, int n_in,
                              void* d_out, int out_size, void* d_ws, size_t ws_size,
                              hipStream_t stream) {
    const float* x = (const float*)d_in[0];
    const float* w = (const float*)d_in[1];
    float* out = (float*)d_out;
    __bf16* wbt = (__bf16*)d_ws;   // 9*256*256 bf16 = 1.18 MB

    // binarize + transpose weights into workspace
    binw_kernel<<<9 * CIN, COUT, 0, stream>>>(w, wbt);
    // implicit GEMM
    conv_kernel<<<NPIX / BM, 512, 0, stream>>>(x, wbt, out);
}

// Round 2
// 206.071 us; speedup vs baseline: 1.2824x; 1.2824x over previous
//
#include <hip/hip_runtime.h>
#include <hip/hip_bf16.h>

typedef __bf16 bf16x8 __attribute__((ext_vector_type(8)));
typedef float  f32x4  __attribute__((ext_vector_type(4)));

#define NPIX  100352   // 32*56*56
#define CIN   256
#define COUT  256

#define WBT_OFF 0u
#define ZP_OFF  (2u*1024u*1024u)
#define XB_OFF  (ZP_OFF + 65536u)
#define WS_NEED ((size_t)XB_OFF + (size_t)NPIX * CIN * 2)

// ---- prepass 1: binarize weights -> [tap][cout][cin] bf16; block 0 zeroes zp ----
__global__ void binw_kernel(const float* __restrict__ w, __bf16* __restrict__ wbt,
                            float* __restrict__ zp) {
    if (zp != nullptr && blockIdx.x == 0)
        ((f32x4*)zp)[threadIdx.x] = (f32x4){0.f, 0.f, 0.f, 0.f};
    const int cout = threadIdx.x;          // 0..255
    const int rc   = blockIdx.x;           // tap*256 + cin
    const float v  = w[(size_t)rc * COUT + cout];
    const float s  = (v > 0.f) ? 1.f : ((v < 0.f) ? -1.f : 0.f);
    const int tap = rc >> 8;
    const int cin = rc & 255;
    wbt[((size_t)(tap * COUT + cout)) * CIN + cin] = (__bf16)s;
}

// ---- prepass 2: x f32 -> bf16 (same [pixel][cin] layout) ----
__global__ __launch_bounds__(256) void xcvt_kernel(const float* __restrict__ x,
                                                   __bf16* __restrict__ xb) {
    const size_t i = (size_t)blockIdx.x * 256 + threadIdx.x;  // chunk of 8 elems
    const f32x4* s = (const f32x4*)(x + i * 8);
    const f32x4 a = s[0], b = s[1];
    bf16x8 v;
    #pragma unroll
    for (int j = 0; j < 4; ++j) { v[j] = (__bf16)a[j]; v[j + 4] = (__bf16)b[j]; }
    *(bf16x8*)(xb + i * 8) = v;
}

__device__ __forceinline__ void gll16(const __bf16* g, __bf16* l) {
    __builtin_amdgcn_global_load_lds(
        (const __attribute__((address_space(1))) void*)g,
        (__attribute__((address_space(3))) void*)l, 16, 0, 0);
}

// ---- main: m97-structure implicit GEMM, 128x128 tile, BK=64, 9 taps x 4 ks ----
__global__ __launch_bounds__(256, 3) void conv_mfma(const __bf16* __restrict__ xb,
                                                    const __bf16* __restrict__ wbt,
                                                    const __bf16* __restrict__ zp,
                                                    float* __restrict__ out) {
    __shared__ __bf16 Alds[128 * 64];   // linear, swizzled contents
    __shared__ __bf16 Blds[128 * 64];

    const int tid  = threadIdx.x;
    const int lane = tid & 63;
    const int wave = tid >> 6;              // 0..3
    const int m_base = (wave >> 1) * 64;
    const int n_base = (wave & 1) * 64;
    const int lr   = lane & 15;
    const int kseg = lane >> 4;             // 0..3

    const int bm = blockIdx.x >> 1;         // 0..783 (consecutive pair shares A-tile)
    const int bn = blockIdx.x & 1;          // 0..1

    // staging identity: issue j covers rows j*32..j*32+31; this lane owns
    // row j*32+srow, 8-elem slot (l&7), fetched from swizzled source slot swz8
    const int srow = wave * 8 + (lane >> 3);      // 0..31
    const int swz8 = (lane & 7) ^ (lane >> 3);    // involution: slot ^ (row&7)

    int hh[4], ww[4];
    const __bf16* apix[4];
    #pragma unroll
    for (int j = 0; j < 4; ++j) {
        const int p = bm * 128 + j * 32 + srow;
        const int rem = p % 3136;
        hh[j] = rem / 56;
        ww[j] = rem % 56;
        apix[j] = xb + (size_t)p * CIN + swz8 * 8;
    }
    size_t bofs[4];
    #pragma unroll
    for (int j = 0; j < 4; ++j)
        bofs[j] = (size_t)(bn * 128 + j * 32 + srow) * CIN + swz8 * 8;

    // swizzled LDS frag-read element offsets: row*64 + ((kf*4+kseg)^(row&7))*8
    int aoffs[4][2], boffs[4][2];
    #pragma unroll
    for (int f = 0; f < 4; ++f)
        #pragma unroll
        for (int kf = 0; kf < 2; ++kf) {
            const int slot = (kf * 4 + kseg) ^ (lr & 7);
            aoffs[f][kf] = (m_base + f * 16 + lr) * 64 + slot * 8;
            boffs[f][kf] = (n_base + f * 16 + lr) * 64 + slot * 8;
        }

    f32x4 acc[4][4];
    #pragma unroll
    for (int i = 0; i < 4; ++i)
        #pragma unroll
        for (int j = 0; j < 4; ++j)
            acc[i][j] = (f32x4){0.f, 0.f, 0.f, 0.f};

    for (int tap = 0; tap < 9; ++tap) {
        const int dh = tap / 3 - 1;
        const int dw = tap % 3 - 1;
        const int doff = (dh * 56 + dw) * CIN;
        const __bf16* asrc[4];
        #pragma unroll
        for (int j = 0; j < 4; ++j) {
            const bool valid = ((unsigned)(hh[j] + dh) < 56u) & ((unsigned)(ww[j] + dw) < 56u);
            asrc[j] = valid ? (apix[j] + doff) : (zp + swz8 * 8);
        }
        const __bf16* bsrc = wbt + (size_t)tap * COUT * CIN;

        #pragma unroll
        for (int ks = 0; ks < 4; ++ks) {
            const int c0 = ks * 64;
            __syncthreads();   // previous step's frag reads complete
            #pragma unroll
            for (int j = 0; j < 4; ++j) {
                gll16(asrc[j] + c0, Alds + j * 2048 + wave * 512);
                gll16(bsrc + bofs[j] + c0, Blds + j * 2048 + wave * 512);
            }
            __syncthreads();   // vmcnt(0) drain + barrier: tile ready

            bf16x8 af[4][2], bfr[4][2];
            #pragma unroll
            for (int mf = 0; mf < 4; ++mf)
                #pragma unroll
                for (int kf = 0; kf < 2; ++kf)
                    af[mf][kf] = *(const bf16x8*)(Alds + aoffs[mf][kf]);
            #pragma unroll
            for (int nf = 0; nf < 4; ++nf)
                #pragma unroll
                for (int kf = 0; kf < 2; ++kf)
                    bfr[nf][kf] = *(const bf16x8*)(Blds + boffs[nf][kf]);

            #pragma unroll
            for (int kf = 0; kf < 2; ++kf)
                #pragma unroll
                for (int mf = 0; mf < 4; ++mf)
                    #pragma unroll
                    for (int nf = 0; nf < 4; ++nf)
                        acc[mf][nf] = __builtin_amdgcn_mfma_f32_16x16x32_bf16(
                            af[mf][kf], bfr[nf][kf], acc[mf][nf], 0, 0, 0);
        }
    }

    // epilogue: C/D map col=lane&15, row=(lane>>4)*4+j
    const int row0 = bm * 128 + m_base + (lane >> 4) * 4;
    const int col0 = bn * 128 + n_base + lr;
    #pragma unroll
    for (int mf = 0; mf < 4; ++mf)
        #pragma unroll
        for (int nf = 0; nf < 4; ++nf) {
            const int r = row0 + mf * 16;
            const int c = col0 + nf * 16;
            #pragma unroll
            for (int j = 0; j < 4; ++j)
                out[(size_t)(r + j) * COUT + c] = acc[mf][nf][j];
        }
}

// ---- fallback (round-1 kernel) if ws too small for bf16-x ----
__global__ __launch_bounds__(512) void conv_fb(const float* __restrict__ x,
                                               const __bf16* __restrict__ wbt,
                                               float* __restrict__ out) {
    __shared__ __bf16 Alds[128][72];
    __shared__ __bf16 Blds[256][72];

    const int tid  = threadIdx.x;
    const int lane = tid & 63;
    const int wave = tid >> 6;
    const int m_base = (wave >> 2) * 64;
    const int n_base = (wave & 3) * 64;
    const int lr = lane & 15;
    const int kb = (lane >> 4) * 8;

    const int arow = tid >> 2;
    const int aseg = tid & 3;
    const int p    = blockIdx.x * 128 + arow;
    const int rem  = p % 3136;
    const int h    = rem / 56;
    const int wc   = rem % 56;

    f32x4 acc[4][4];
    #pragma unroll
    for (int i = 0; i < 4; ++i)
        #pragma unroll
        for (int j = 0; j < 4; ++j)
            acc[i][j] = (f32x4){0.f, 0.f, 0.f, 0.f};

    for (int tap = 0; tap < 9; ++tap) {
        const int dh = tap / 3 - 1;
        const int dw = tap % 3 - 1;
        const bool valid = ((unsigned)(h + dh) < 56u) && ((unsigned)(wc + dw) < 56u);
        const long aoff = ((long)p + (long)dh * 56 + dw) * CIN + aseg * 16;
        const __bf16* bsrc = wbt + (size_t)tap * COUT * CIN;

        #pragma unroll
        for (int ks = 0; ks < 4; ++ks) {
            const int c0 = ks * 64;
            __syncthreads();
            f32x4 f0, f1, f2, f3;
            if (valid) {
                const f32x4* s4 = (const f32x4*)(x + aoff + c0);
                f0 = s4[0]; f1 = s4[1]; f2 = s4[2]; f3 = s4[3];
            } else {
                f0 = f1 = f2 = f3 = (f32x4){0.f, 0.f, 0.f, 0.f};
            }
            bf16x8 v0, v1;
            #pragma unroll
            for (int j = 0; j < 4; ++j) {
                v0[j] = (__bf16)f0[j]; v0[j + 4] = (__bf16)f1[j];
                v1[j] = (__bf16)f2[j]; v1[j + 4] = (__bf16)f3[j];
            }
            *(bf16x8*)&Alds[arow][aseg * 16]     = v0;
            *(bf16x8*)&Alds[arow][aseg * 16 + 8] = v1;
            #pragma unroll
            for (int i = 0; i < 4; ++i) {
                const int chunk = tid + i * 512;
                const int row = chunk >> 3;
                const int cs  = chunk & 7;
                *(uint4*)&Blds[row][cs * 8] = *(const uint4*)(bsrc + row * CIN + c0 + cs * 8);
            }
            __syncthreads();

            bf16x8 af[4][2], bfr[4][2];
            #pragma unroll
            for (int mf = 0; mf < 4; ++mf)
                #pragma unroll
                for (int kf = 0; kf < 2; ++kf)
                    af[mf][kf] = *(const bf16x8*)&Alds[m_base + mf * 16 + lr][kf * 32 + kb];
            #pragma unroll
            for (int nf = 0; nf < 4; ++nf)
                #pragma unroll
                for (int kf = 0; kf < 2; ++kf)
                    bfr[nf][kf] = *(const bf16x8*)&Blds[n_base + nf * 16 + lr][kf * 32 + kb];
            #pragma unroll
            for (int kf = 0; kf < 2; ++kf)
                #pragma unroll
                for (int mf = 0; mf < 4; ++mf)
                    #pragma unroll
                    for (int nf = 0; nf < 4; ++nf)
                        acc[mf][nf] = __builtin_amdgcn_mfma_f32_16x16x32_bf16(
                            af[mf][kf], bfr[nf][kf], acc[mf][nf], 0, 0, 0);
        }
    }
    #pragma unroll
    for (int mf = 0; mf < 4; ++mf)
        #pragma unroll
        for (int nf = 0; nf < 4; ++nf) {
            const int r0 = blockIdx.x * 128 + m_base + mf * 16 + (lane >> 4) * 4;
            const int c  = n_base + nf * 16 + lr;
            #pragma unroll
            for (int j = 0; j < 4; ++j)
                out[(size_t)(r0 + j) * COUT + c] = acc[mf][nf][j];
        }
}

extern "C" void kernel_launch(void* const* d_in, const int* in_sizes, int n_in,
                              void* d_out, int out_size, void* d_ws, size_t ws_size,
                              hipStream_t stream) {
    const float* x = (const float*)d_in[0];
    const float* w = (const float*)d_in[1];
    float* out = (float*)d_out;
    char* ws = (char*)d_ws;
    __bf16* wbt = (__bf16*)(ws + WBT_OFF);

    const bool fast = ws_size >= WS_NEED;
    float* zp = fast ? (float*)(ws + ZP_OFF) : nullptr;

    binw_kernel<<<9 * CIN, COUT, 0, stream>>>(w, wbt, zp);
    if (fast) {
        __bf16* xb = (__bf16*)(ws + XB_OFF);
        xcvt_kernel<<<NPIX * CIN / 8 / 256, 256, 0, stream>>>(x, xb);
        conv_mfma<<<(NPIX / 128) * 2, 256, 0, stream>>>(xb, wbt, (const __bf16*)(ws + ZP_OFF), out);
    } else {
        conv_fb<<<NPIX / 128, 512, 0, stream>>>(x, wbt, out);
    }
}

// Round 3
// 151.864 us; speedup vs baseline: 1.7402x; 1.3569x over previous
//
#include <hip/hip_runtime.h>
#include <hip/hip_bf16.h>

typedef __bf16 bf16x8 __attribute__((ext_vector_type(8)));
typedef float  f32x4  __attribute__((ext_vector_type(4)));

#define NPIX  100352   // 32*56*56
#define CIN   256
#define COUT  256

#define WBT_OFF 0u
#define ZP_OFF  (2u*1024u*1024u)
#define XB_OFF  (ZP_OFF + 65536u)
#define XPAD_ELEMS ((size_t)32*3364*256)            // 58x58 padded, bf16
#define WS_NEED8 ((size_t)XB_OFF + XPAD_ELEMS*2)
#define WS_NEED1 ((size_t)XB_OFF + (size_t)NPIX*CIN*2)

#define BAR() do { asm volatile("" ::: "memory"); __builtin_amdgcn_s_barrier(); asm volatile("" ::: "memory"); } while(0)

// ---- prepass 1: binarize weights -> [tap][cout][cin] bf16; block 0 zeroes zp ----
__global__ void binw_kernel(const float* __restrict__ w, __bf16* __restrict__ wbt,
                            float* __restrict__ zp) {
    if (zp != nullptr && blockIdx.x == 0)
        ((f32x4*)zp)[threadIdx.x] = (f32x4){0.f, 0.f, 0.f, 0.f};
    const int cout = threadIdx.x;
    const int rc   = blockIdx.x;           // tap*256 + cin
    const float v  = w[(size_t)rc * COUT + cout];
    const float s  = (v > 0.f) ? 1.f : ((v < 0.f) ? -1.f : 0.f);
    const int tap = rc >> 8;
    const int cin = rc & 255;
    wbt[((size_t)(tap * COUT + cout)) * CIN + cin] = (__bf16)s;
}

// ---- prepass 2a: x f32 -> zero-padded bf16 [32][58][58][256] ----
__global__ __launch_bounds__(256) void xpad_kernel(const float* __restrict__ x,
                                                   __bf16* __restrict__ xp) {
    const int g = blockIdx.x * 256 + threadIdx.x;   // chunk of 8 channels
    const int prow = g >> 5, cseg = g & 31;
    const int b = prow / 3364, rr = prow % 3364;
    const int ph = rr / 58, pw = rr % 58;
    bf16x8 v = {};
    if (ph >= 1 && ph <= 56 && pw >= 1 && pw <= 56) {
        const size_t s = ((size_t)b * 3136 + (size_t)(ph - 1) * 56 + (pw - 1)) * 256 + cseg * 8;
        const f32x4 a = *(const f32x4*)(x + s);
        const f32x4 c = *(const f32x4*)(x + s + 4);
        #pragma unroll
        for (int j = 0; j < 4; ++j) { v[j] = (__bf16)a[j]; v[j + 4] = (__bf16)c[j]; }
    }
    *(bf16x8*)(xp + (size_t)g * 8) = v;
}

// ---- prepass 2b (fallback): x f32 -> bf16, unpadded ----
__global__ __launch_bounds__(256) void xcvt_kernel(const float* __restrict__ x,
                                                   __bf16* __restrict__ xb) {
    const size_t i = (size_t)blockIdx.x * 256 + threadIdx.x;
    const f32x4* s = (const f32x4*)(x + i * 8);
    const f32x4 a = s[0], b = s[1];
    bf16x8 v;
    #pragma unroll
    for (int j = 0; j < 4; ++j) { v[j] = (__bf16)a[j]; v[j + 4] = (__bf16)b[j]; }
    *(bf16x8*)(xb + i * 8) = v;
}

__device__ __forceinline__ void gll16(const __bf16* g, __bf16* l) {
    __builtin_amdgcn_global_load_lds(
        (const __attribute__((address_space(1))) void*)g,
        (__attribute__((address_space(3))) void*)l, 16, 0, 0);
}

// =====================  8-phase 256x256 kernel  =====================
// LDS element offsets (bf16)
#define SA0 0
#define SB0 16384
#define SA1 32768
#define SB1 49152

__device__ __forceinline__ void stageA(const __bf16* p0, const __bf16* p1,
                                       __bf16* d0, __bf16* d1, int ts) {
    const int tap = ts >> 2;
    const int dh1 = (tap * 11) >> 5;          // tap/3
    const int off = ((dh1 - 1) * 58 + (tap - dh1 * 3 - 1)) * 256 + ((ts & 3) << 6);
    gll16(p0 + off, d0);
    gll16(p1 + off, d1);
}
__device__ __forceinline__ void stageB(const __bf16* wbt, int b0, int b1,
                                       __bf16* d0, __bf16* d1, int ts) {
    const __bf16* s = wbt + ((ts >> 2) << 16) + ((ts & 3) << 6);
    gll16(s + b0, d0);
    gll16(s + b1, d1);
}

__global__ __launch_bounds__(512, 2) void conv8p(const __bf16* __restrict__ xp,
                                                 const __bf16* __restrict__ wbt,
                                                 float* __restrict__ out) {
    __shared__ __bf16 lds[65536];   // 128 KB: A0,B0,A1,B1 each 256x64

    const int tid  = threadIdx.x;
    const int lane = tid & 63;
    const int wave = tid >> 6;                  // 0..7
    const int l3 = lane >> 3, l7 = lane & 7;
    const int srcslot = l7 ^ l3;                // source swizzle involution
    const int lr = lane & 15, kseg = lane >> 4;

    const int bid = blockIdx.x;                 // 392 blocks, 392%8==0
    const int bm  = (bid & 7) * 49 + (bid >> 3);

    // ---- staging geometry: half h covers rows {64h..64h+63} U {128+64h..} ----
    const __bf16* pA[2][2];
    int bOf[2][2], dOf[2][2];
    #pragma unroll
    for (int h = 0; h < 2; ++h)
        #pragma unroll
        for (int j = 0; j < 2; ++j) {
            const int rb = 64 * h + (wave >> 2) * 128 + (wave & 3) * 16 + 8 * j;
            dOf[h][j] = rb * 64;                       // wave-uniform LDS elem offset
            const int r = rb + l3;                     // per-lane row
            bOf[h][j] = r * 256 + srcslot * 8;
            const int p = bm * 256 + r;
            const int b = p / 3136, rem = p % 3136;
            const int hh = rem / 56, ww = rem % 56;
            pA[h][j] = xp + ((size_t)b * 3364 + (size_t)(hh + 1) * 58 + (ww + 1)) * 256
                          + srcslot * 8;
        }

    // ---- read addresses (element offsets within each 256x64 region) ----
    const int slot0 = ((kseg)     ^ (lr & 7)) * 8;     // kf=0
    const int slot1 = ((4 + kseg) ^ (lr & 7)) * 8;     // kf=1
    const int aB = ((wave >> 2) * 128 + lr) * 64;
    const int bB = ((wave & 3) * 64 + lr) * 64;
    const int aK0 = aB + slot0, aK1 = aB + slot1;
    const int bK0 = bB + slot0, bK1 = bB + slot1;

    f32x4 acc[8][4];
    #pragma unroll
    for (int f = 0; f < 8; ++f)
        #pragma unroll
        for (int n = 0; n < 4; ++n)
            acc[f][n] = (f32x4){0.f, 0.f, 0.f, 0.f};

    // ---- prologue: stage t0 fully + t1 {B0,B1,A0} = 7 half-tiles (14 vmem/wave) ----
    stageB(wbt, bOf[0][0], bOf[0][1], &lds[SB0 + dOf[0][0]], &lds[SB0 + dOf[0][1]], 0);
    stageB(wbt, bOf[1][0], bOf[1][1], &lds[SB0 + dOf[1][0]], &lds[SB0 + dOf[1][1]], 0);
    stageA(pA[0][0], pA[0][1], &lds[SA0 + dOf[0][0]], &lds[SA0 + dOf[0][1]], 0);
    stageA(pA[1][0], pA[1][1], &lds[SA0 + dOf[1][0]], &lds[SA0 + dOf[1][1]], 0);
    stageB(wbt, bOf[0][0], bOf[0][1], &lds[SB1 + dOf[0][0]], &lds[SB1 + dOf[0][1]], 1);
    stageB(wbt, bOf[1][0], bOf[1][1], &lds[SB1 + dOf[1][0]], &lds[SB1 + dOf[1][1]], 1);
    stageA(pA[0][0], pA[0][1], &lds[SA1 + dOf[0][0]], &lds[SA1 + dOf[0][1]], 1);
    asm volatile("s_waitcnt vmcnt(6)" ::: "memory");
    BAR();

    bf16x8 bk0[4], bk1[4];

    for (int i = 0; i < 18; ++i) {
        const bool last = (i == 17);
        const int te = 2 * i + 2;     // next even K-step (-> dbuf0)
        const int to = 2 * i + 3;     // next odd K-step (-> dbuf1)

        // ================= phase 1: A(buf0,fh0,kf0) + all B(buf0); stage A1(2i+1) =================
        {
            bf16x8 af[4];
            #pragma unroll
            for (int f = 0; f < 4; ++f) af[f] = *(const bf16x8*)&lds[SA0 + aK0 + f * 1024];
            #pragma unroll
            for (int n = 0; n < 4; ++n) {
                bk0[n] = *(const bf16x8*)&lds[SB0 + bK0 + n * 1024];
                bk1[n] = *(const bf16x8*)&lds[SB0 + bK1 + n * 1024];
            }
            stageA(pA[1][0], pA[1][1], &lds[SA1 + dOf[1][0]], &lds[SA1 + dOf[1][1]], 2 * i + 1);
            BAR();
            __builtin_amdgcn_s_setprio(1);
            #pragma unroll
            for (int f = 0; f < 4; ++f)
                #pragma unroll
                for (int n = 0; n < 4; ++n)
                    acc[f][n] = __builtin_amdgcn_mfma_f32_16x16x32_bf16(af[f], bk0[n], acc[f][n], 0, 0, 0);
            __builtin_amdgcn_s_setprio(0);
            BAR();
        }
        // ================= phase 2: A(buf0,fh0,kf1); stage B0(te) =================
        {
            bf16x8 af[4];
            #pragma unroll
            for (int f = 0; f < 4; ++f) af[f] = *(const bf16x8*)&lds[SA0 + aK1 + f * 1024];
            if (!last) stageB(wbt, bOf[0][0], bOf[0][1], &lds[SB0 + dOf[0][0]], &lds[SB0 + dOf[0][1]], te);
            BAR();
            __builtin_amdgcn_s_setprio(1);
            #pragma unroll
            for (int f = 0; f < 4; ++f)
                #pragma unroll
                for (int n = 0; n < 4; ++n)
                    acc[f][n] = __builtin_amdgcn_mfma_f32_16x16x32_bf16(af[f], bk1[n], acc[f][n], 0, 0, 0);
            __builtin_amdgcn_s_setprio(0);
            BAR();
        }
        // ================= phase 3: A(buf0,fh1,kf0); stage B1(te) =================
        {
            bf16x8 af[4];
            #pragma unroll
            for (int f = 0; f < 4; ++f) af[f] = *(const bf16x8*)&lds[SA0 + aK0 + (f + 4) * 1024];
            if (!last) stageB(wbt, bOf[1][0], bOf[1][1], &lds[SB0 + dOf[1][0]], &lds[SB0 + dOf[1][1]], te);
            BAR();
            __builtin_amdgcn_s_setprio(1);
            #pragma unroll
            for (int f = 0; f < 4; ++f)
                #pragma unroll
                for (int n = 0; n < 4; ++n)
                    acc[f + 4][n] = __builtin_amdgcn_mfma_f32_16x16x32_bf16(af[f], bk0[n], acc[f + 4][n], 0, 0, 0);
            __builtin_amdgcn_s_setprio(0);
            BAR();
        }
        // ================= phase 4: A(buf0,fh1,kf1); stage A0(te); vmcnt =================
        {
            bf16x8 af[4];
            #pragma unroll
            for (int f = 0; f < 4; ++f) af[f] = *(const bf16x8*)&lds[SA0 + aK1 + (f + 4) * 1024];
            if (!last) {
                stageA(pA[0][0], pA[0][1], &lds[SA0 + dOf[0][0]], &lds[SA0 + dOf[0][1]], te);
                asm volatile("s_waitcnt vmcnt(6)" ::: "memory");
            } else {
                asm volatile("s_waitcnt vmcnt(0)" ::: "memory");
            }
            BAR();
            __builtin_amdgcn_s_setprio(1);
            #pragma unroll
            for (int f = 0; f < 4; ++f)
                #pragma unroll
                for (int n = 0; n < 4; ++n)
                    acc[f + 4][n] = __builtin_amdgcn_mfma_f32_16x16x32_bf16(af[f], bk1[n], acc[f + 4][n], 0, 0, 0);
            __builtin_amdgcn_s_setprio(0);
            BAR();
        }
        // ================= phase 5: A(buf1,fh0,kf0) + all B(buf1); stage A1(te) =================
        {
            bf16x8 af[4];
            #pragma unroll
            for (int f = 0; f < 4; ++f) af[f] = *(const bf16x8*)&lds[SA1 + aK0 + f * 1024];
            #pragma unroll
            for (int n = 0; n < 4; ++n) {
                bk0[n] = *(const bf16x8*)&lds[SB1 + bK0 + n * 1024];
                bk1[n] = *(const bf16x8*)&lds[SB1 + bK1 + n * 1024];
            }
            if (!last) stageA(pA[1][0], pA[1][1], &lds[SA0 + dOf[1][0]], &lds[SA0 + dOf[1][1]], te);
            BAR();
            __builtin_amdgcn_s_setprio(1);
            #pragma unroll
            for (int f = 0; f < 4; ++f)
                #pragma unroll
                for (int n = 0; n < 4; ++n)
                    acc[f][n] = __builtin_amdgcn_mfma_f32_16x16x32_bf16(af[f], bk0[n], acc[f][n], 0, 0, 0);
            __builtin_amdgcn_s_setprio(0);
            BAR();
        }
        // ================= phase 6: A(buf1,fh0,kf1); stage B0(to) =================
        {
            bf16x8 af[4];
            #pragma unroll
            for (int f = 0; f < 4; ++f) af[f] = *(const bf16x8*)&lds[SA1 + aK1 + f * 1024];
            if (!last) stageB(wbt, bOf[0][0], bOf[0][1], &lds[SB1 + dOf[0][0]], &lds[SB1 + dOf[0][1]], to);
            BAR();
            __builtin_amdgcn_s_setprio(1);
            #pragma unroll
            for (int f = 0; f < 4; ++f)
                #pragma unroll
                for (int n = 0; n < 4; ++n)
                    acc[f][n] = __builtin_amdgcn_mfma_f32_16x16x32_bf16(af[f], bk1[n], acc[f][n], 0, 0, 0);
            __builtin_amdgcn_s_setprio(0);
            BAR();
        }
        // ================= phase 7: A(buf1,fh1,kf0); stage B1(to) =================
        {
            bf16x8 af[4];
            #pragma unroll
            for (int f = 0; f < 4; ++f) af[f] = *(const bf16x8*)&lds[SA1 + aK0 + (f + 4) * 1024];
            if (!last) stageB(wbt, bOf[1][0], bOf[1][1], &lds[SB1 + dOf[1][0]], &lds[SB1 + dOf[1][1]], to);
            BAR();
            __builtin_amdgcn_s_setprio(1);
            #pragma unroll
            for (int f = 0; f < 4; ++f)
                #pragma unroll
                for (int n = 0; n < 4; ++n)
                    acc[f + 4][n] = __builtin_amdgcn_mfma_f32_16x16x32_bf16(af[f], bk0[n], acc[f + 4][n], 0, 0, 0);
            __builtin_amdgcn_s_setprio(0);
            BAR();
        }
        // ================= phase 8: A(buf1,fh1,kf1); stage A0(to); vmcnt =================
        {
            bf16x8 af[4];
            #pragma unroll
            for (int f = 0; f < 4; ++f) af[f] = *(const bf16x8*)&lds[SA1 + aK1 + (f + 4) * 1024];
            if (!last) {
                stageA(pA[0][0], pA[0][1], &lds[SA1 + dOf[0][0]], &lds[SA1 + dOf[0][1]], to);
                asm volatile("s_waitcnt vmcnt(6)" ::: "memory");
            }
            BAR();
            __builtin_amdgcn_s_setprio(1);
            #pragma unroll
            for (int f = 0; f < 4; ++f)
                #pragma unroll
                for (int n = 0; n < 4; ++n)
                    acc[f + 4][n] = __builtin_amdgcn_mfma_f32_16x16x32_bf16(af[f], bk1[n], acc[f + 4][n], 0, 0, 0);
            __builtin_amdgcn_s_setprio(0);
            BAR();
        }
    }

    // ---- epilogue: C/D map col=lane&15, row=(lane>>4)*4+j ----
    const int row0 = bm * 256 + (wave >> 2) * 128 + (lane >> 4) * 4;
    const int col0 = (wave & 3) * 64 + lr;
    #pragma unroll
    for (int f = 0; f < 8; ++f)
        #pragma unroll
        for (int n = 0; n < 4; ++n) {
            const int r = row0 + f * 16;
            const int c = col0 + n * 16;
            #pragma unroll
            for (int j = 0; j < 4; ++j)
                out[(size_t)(r + j) * COUT + c] = acc[f][n][j];
        }
}

// =====================  fallback 1: round-2 m97-structure kernel  =====================
__global__ __launch_bounds__(256, 3) void conv_mfma(const __bf16* __restrict__ xb,
                                                    const __bf16* __restrict__ wbt,
                                                    const __bf16* __restrict__ zp,
                                                    float* __restrict__ out) {
    __shared__ __bf16 Alds[128 * 64];
    __shared__ __bf16 Blds[128 * 64];

    const int tid  = threadIdx.x;
    const int lane = tid & 63;
    const int wave = tid >> 6;
    const int m_base = (wave >> 1) * 64;
    const int n_base = (wave & 1) * 64;
    const int lr   = lane & 15;
    const int kseg = lane >> 4;

    const int bm = blockIdx.x >> 1;
    const int bn = blockIdx.x & 1;

    const int srow = wave * 8 + (lane >> 3);
    const int swz8 = (lane & 7) ^ (lane >> 3);

    int hh[4], ww[4];
    const __bf16* apix[4];
    #pragma unroll
    for (int j = 0; j < 4; ++j) {
        const int p = bm * 128 + j * 32 + srow;
        const int rem = p % 3136;
        hh[j] = rem / 56;
        ww[j] = rem % 56;
        apix[j] = xb + (size_t)p * CIN + swz8 * 8;
    }
    size_t bofs[4];
    #pragma unroll
    for (int j = 0; j < 4; ++j)
        bofs[j] = (size_t)(bn * 128 + j * 32 + srow) * CIN + swz8 * 8;

    int aoffs[4][2], boffs[4][2];
    #pragma unroll
    for (int f = 0; f < 4; ++f)
        #pragma unroll
        for (int kf = 0; kf < 2; ++kf) {
            const int slot = (kf * 4 + kseg) ^ (lr & 7);
            aoffs[f][kf] = (m_base + f * 16 + lr) * 64 + slot * 8;
            boffs[f][kf] = (n_base + f * 16 + lr) * 64 + slot * 8;
        }

    f32x4 acc[4][4];
    #pragma unroll
    for (int i = 0; i < 4; ++i)
        #pragma unroll
        for (int j = 0; j < 4; ++j)
            acc[i][j] = (f32x4){0.f, 0.f, 0.f, 0.f};

    for (int tap = 0; tap < 9; ++tap) {
        const int dh = tap / 3 - 1;
        const int dw = tap % 3 - 1;
        const int doff = (dh * 56 + dw) * CIN;
        const __bf16* asrc[4];
        #pragma unroll
        for (int j = 0; j < 4; ++j) {
            const bool valid = ((unsigned)(hh[j] + dh) < 56u) & ((unsigned)(ww[j] + dw) < 56u);
            asrc[j] = valid ? (apix[j] + doff) : (zp + swz8 * 8);
        }
        const __bf16* bsrc = wbt + (size_t)tap * COUT * CIN;

        #pragma unroll
        for (int ks = 0; ks < 4; ++ks) {
            const int c0 = ks * 64;
            __syncthreads();
            #pragma unroll
            for (int j = 0; j < 4; ++j) {
                gll16(asrc[j] + c0, Alds + j * 2048 + wave * 512);
                gll16(bsrc + bofs[j] + c0, Blds + j * 2048 + wave * 512);
            }
            __syncthreads();

            bf16x8 af[4][2], bfr[4][2];
            #pragma unroll
            for (int mf = 0; mf < 4; ++mf)
                #pragma unroll
                for (int kf = 0; kf < 2; ++kf)
                    af[mf][kf] = *(const bf16x8*)(Alds + aoffs[mf][kf]);
            #pragma unroll
            for (int nf = 0; nf < 4; ++nf)
                #pragma unroll
                for (int kf = 0; kf < 2; ++kf)
                    bfr[nf][kf] = *(const bf16x8*)(Blds + boffs[nf][kf]);

            #pragma unroll
            for (int kf = 0; kf < 2; ++kf)
                #pragma unroll
                for (int mf = 0; mf < 4; ++mf)
                    #pragma unroll
                    for (int nf = 0; nf < 4; ++nf)
                        acc[mf][nf] = __builtin_amdgcn_mfma_f32_16x16x32_bf16(
                            af[mf][kf], bfr[nf][kf], acc[mf][nf], 0, 0, 0);
        }
    }

    const int row0 = bm * 128 + m_base + (lane >> 4) * 4;
    const int col0 = bn * 128 + n_base + lr;
    #pragma unroll
    for (int mf = 0; mf < 4; ++mf)
        #pragma unroll
        for (int nf = 0; nf < 4; ++nf) {
            const int r = row0 + mf * 16;
            const int c = col0 + nf * 16;
            #pragma unroll
            for (int j = 0; j < 4; ++j)
                out[(size_t)(r + j) * COUT + c] = acc[mf][nf][j];
        }
}

// =====================  fallback 2: reg-staged (tiny ws)  =====================
__global__ __launch_bounds__(512) void conv_fb(const float* __restrict__ x,
                                               const __bf16* __restrict__ wbt,
                                               float* __restrict__ out) {
    __shared__ __bf16 Alds[128][72];
    __shared__ __bf16 Blds[256][72];

    const int tid  = threadIdx.x;
    const int lane = tid & 63;
    const int wave = tid >> 6;
    const int m_base = (wave >> 2) * 64;
    const int n_base = (wave & 3) * 64;
    const int lr = lane & 15;
    const int kb = (lane >> 4) * 8;

    const int arow = tid >> 2;
    const int aseg = tid & 3;
    const int p    = blockIdx.x * 128 + arow;
    const int rem  = p % 3136;
    const int h    = rem / 56;
    const int wc   = rem % 56;

    f32x4 acc[4][4];
    #pragma unroll
    for (int i = 0; i < 4; ++i)
        #pragma unroll
        for (int j = 0; j < 4; ++j)
            acc[i][j] = (f32x4){0.f, 0.f, 0.f, 0.f};

    for (int tap = 0; tap < 9; ++tap) {
        const int dh = tap / 3 - 1;
        const int dw = tap % 3 - 1;
        const bool valid = ((unsigned)(h + dh) < 56u) && ((unsigned)(wc + dw) < 56u);
        const long aoff = ((long)p + (long)dh * 56 + dw) * CIN + aseg * 16;
        const __bf16* bsrc = wbt + (size_t)tap * COUT * CIN;

        #pragma unroll
        for (int ks = 0; ks < 4; ++ks) {
            const int c0 = ks * 64;
            __syncthreads();
            f32x4 f0, f1, f2, f3;
            if (valid) {
                const f32x4* s4 = (const f32x4*)(x + aoff + c0);
                f0 = s4[0]; f1 = s4[1]; f2 = s4[2]; f3 = s4[3];
            } else {
                f0 = f1 = f2 = f3 = (f32x4){0.f, 0.f, 0.f, 0.f};
            }
            bf16x8 v0, v1;
            #pragma unroll
            for (int j = 0; j < 4; ++j) {
                v0[j] = (__bf16)f0[j]; v0[j + 4] = (__bf16)f1[j];
                v1[j] = (__bf16)f2[j]; v1[j + 4] = (__bf16)f3[j];
            }
            *(bf16x8*)&Alds[arow][aseg * 16]     = v0;
            *(bf16x8*)&Alds[arow][aseg * 16 + 8] = v1;
            #pragma unroll
            for (int i = 0; i < 4; ++i) {
                const int chunk = tid + i * 512;
                const int row = chunk >> 3;
                const int cs  = chunk & 7;
                *(uint4*)&Blds[row][cs * 8] = *(const uint4*)(bsrc + row * CIN + c0 + cs * 8);
            }
            __syncthreads();

            bf16x8 af[4][2], bfr[4][2];
            #pragma unroll
            for (int mf = 0; mf < 4; ++mf)
                #pragma unroll
                for (int kf = 0; kf < 2; ++kf)
                    af[mf][kf] = *(const bf16x8*)&Alds[m_base + mf * 16 + lr][kf * 32 + kb];
            #pragma unroll
            for (int nf = 0; nf < 4; ++nf)
                #pragma unroll
                for (int kf = 0; kf < 2; ++kf)
                    bfr[nf][kf] = *(const bf16x8*)&Blds[n_base + nf * 16 + lr][kf * 32 + kb];
            #pragma unroll
            for (int kf = 0; kf < 2; ++kf)
                #pragma unroll
                for (int mf = 0; mf < 4; ++mf)
                    #pragma unroll
                    for (int nf = 0; nf < 4; ++nf)
                        acc[mf][nf] = __builtin_amdgcn_mfma_f32_16x16x32_bf16(
                            af[mf][kf], bfr[nf][kf], acc[mf][nf], 0, 0, 0);
        }
    }
    #pragma unroll
    for (int mf = 0; mf < 4; ++mf)
        #pragma unroll
        for (int nf = 0; nf < 4; ++nf) {
            const int r0 = blockIdx.x * 128 + m_base + mf * 16 + (lane >> 4) * 4;
            const int c  = n_base + nf * 16 + lr;
            #pragma unroll
            for (int j = 0; j < 4; ++j)
                out[(size_t)(r0 + j) * COUT + c] = acc[mf][nf][j];
        }
}

extern "C" void kernel_launch(void* const* d_in, const int* in_sizes, int n_in,
                              void* d_out, int out_size, void* d_ws, size_t ws_size,
                              hipStream_t stream) {
    const float* x = (const float*)d_in[0];
    const float* w = (const float*)d_in[1];
    float* out = (float*)d_out;
    char* ws = (char*)d_ws;
    __bf16* wbt = (__bf16*)(ws + WBT_OFF);

    if (ws_size >= WS_NEED8) {
        __bf16* xp = (__bf16*)(ws + XB_OFF);
        binw_kernel<<<9 * CIN, COUT, 0, stream>>>(w, wbt, nullptr);
        xpad_kernel<<<13456, 256, 0, stream>>>(x, xp);
        conv8p<<<392, 512, 0, stream>>>(xp, wbt, out);
    } else if (ws_size >= WS_NEED1) {
        float* zp = (float*)(ws + ZP_OFF);
        __bf16* xb = (__bf16*)(ws + XB_OFF);
        binw_kernel<<<9 * CIN, COUT, 0, stream>>>(w, wbt, zp);
        xcvt_kernel<<<NPIX * CIN / 8 / 256, 256, 0, stream>>>(x, xb);
        conv_mfma<<<(NPIX / 128) * 2, 256, 0, stream>>>(xb, wbt, (const __bf16*)(ws + ZP_OFF), out);
    } else {
        binw_kernel<<<9 * CIN, COUT, 0, stream>>>(w, wbt, nullptr);
        conv_fb<<<NPIX / 128, 512, 0, stream>>>(x, wbt, out);
    }
}

// Round 5
// 97.235 us; speedup vs baseline: 2.7178x; 1.5618x over previous
//
#include <hip/hip_runtime.h>
#include <hip/hip_bf16.h>

typedef int    i32x4 __attribute__((ext_vector_type(4)));
typedef float  f32x4 __attribute__((ext_vector_type(4)));
typedef __bf16 bf16x8 __attribute__((ext_vector_type(8)));

#define NPIX  100352   // 32*56*56
#define CIN   256
#define COUT  256

#define QC    4.75f
#define QINV  (127.0f/QC)
#define QDEQ  (QC/127.0f)

#define WBT_OFF 0u
#define XQ_OFF  (1024u*1024u)
#define WS_NEED_I8 ((size_t)XQ_OFF + (size_t)32*3364*256)   // ~28.6 MB

#define BAR() do { asm volatile("" ::: "memory"); __builtin_amdgcn_s_barrier(); asm volatile("" ::: "memory"); } while(0)

// ---- prepass 1: binarize weights -> [tap][cout][cin] i8 ----
__global__ void binw_i8(const float* __restrict__ w, signed char* __restrict__ wbt) {
    const int cout = threadIdx.x;
    const int rc   = blockIdx.x;           // tap*256 + cin
    const float v  = w[(size_t)rc * COUT + cout];
    const signed char s = (v > 0.f) ? 1 : ((v < 0.f) ? -1 : 0);
    const int tap = rc >> 8;
    const int cin = rc & 255;
    wbt[((size_t)(tap * COUT + cout)) * CIN + cin] = s;
}

// ---- prepass 2: x f32 -> quantized i8, zero-padded [32][58][58][256] ----
__global__ __launch_bounds__(256) void xq_kernel(const float* __restrict__ x,
                                                 signed char* __restrict__ xq) {
    const int g = blockIdx.x * 256 + threadIdx.x;   // chunk of 8 channels
    const int prow = g >> 5, cseg = g & 31;
    const int b = prow / 3364, rr = prow % 3364;
    const int ph = rr / 58, pw = rr % 58;
    int2 pack = {0, 0};
    if (ph >= 1 && ph <= 56 && pw >= 1 && pw <= 56) {
        const size_t s = ((size_t)b * 3136 + (size_t)(ph - 1) * 56 + (pw - 1)) * 256 + cseg * 8;
        const f32x4 a = *(const f32x4*)(x + s);
        const f32x4 c = *(const f32x4*)(x + s + 4);
        unsigned lo = 0, hi = 0;
        #pragma unroll
        for (int j = 0; j < 4; ++j) {
            int qa = (int)rintf(fminf(fmaxf(a[j], -QC), QC) * QINV);
            int qc = (int)rintf(fminf(fmaxf(c[j], -QC), QC) * QINV);
            lo |= (unsigned)(qa & 255) << (8 * j);
            hi |= (unsigned)(qc & 255) << (8 * j);
        }
        pack.x = (int)lo; pack.y = (int)hi;
    }
    *(int2*)(xq + (size_t)g * 8) = pack;
}

__device__ __forceinline__ void gll16(const signed char* g, signed char* l) {
    __builtin_amdgcn_global_load_lds(
        (const __attribute__((address_space(1))) void*)g,
        (__attribute__((address_space(3))) void*)l, 16, 0, 0);
}

__device__ __forceinline__ void mfma_i8(i32x4& acc, i32x4 a, i32x4 b) {
    asm("v_mfma_i32_16x16x64_i8 %0, %1, %2, %0" : "+v"(acc) : "v"(a), "v"(b));
}

// =====================  8-phase 256x256 i8 kernel, BK=128  =====================
// LDS byte offsets: A0,B0,A1,B1 each 256 rows x 128 B = 32 KB
#define SA0 0
#define SB0 32768
#define SA1 65536
#define SB1 98304

// ts = tap*2 + ks, ks in {0,1} selects the 128-cin half
__device__ __forceinline__ void stageA(const signed char* p0, const signed char* p1,
                                       signed char* d0, signed char* d1, int ts) {
    const int tap = ts >> 1;
    const int dh1 = (tap * 11) >> 5;          // tap/3
    const int off = ((dh1 - 1) * 58 + (tap - dh1 * 3 - 1)) * 256 + ((ts & 1) << 7);
    gll16(p0 + off, d0);
    gll16(p1 + off, d1);
}
__device__ __forceinline__ void stageB(const signed char* wbt, int b0, int b1,
                                       signed char* d0, signed char* d1, int ts) {
    const signed char* s = wbt + ((ts >> 1) << 16) + ((ts & 1) << 7);
    gll16(s + b0, d0);
    gll16(s + b1, d1);
}

__global__ __launch_bounds__(512, 2) void conv8i(const signed char* __restrict__ xq,
                                                 const signed char* __restrict__ wbt,
                                                 float* __restrict__ out) {
    __shared__ signed char lds[131072];

    const int tid  = threadIdx.x;
    const int lane = tid & 63;
    const int wave = tid >> 6;                  // 0..7
    const int l3 = lane >> 3, l7 = lane & 7;
    const int srcslot = l7 ^ l3;                // source swizzle involution (8 slots x 16B)
    const int lr = lane & 15, kseg = lane >> 4;

    const int bid = blockIdx.x;                 // 392 blocks, 392%8==0
    const int bm  = (bid & 7) * 49 + (bid >> 3);

    // ---- staging geometry: half h covers rows {64h..64h+63} U {128+64h..191+64h} ----
    const signed char* pA[2][2];
    int bOf[2][2], dOf[2][2];
    #pragma unroll
    for (int h = 0; h < 2; ++h)
        #pragma unroll
        for (int j = 0; j < 2; ++j) {
            const int rb = 64 * h + (wave >> 2) * 128 + (wave & 3) * 16 + 8 * j;
            dOf[h][j] = rb * 128;                      // wave-uniform LDS byte offset
            const int r = rb + l3;                     // per-lane row
            bOf[h][j] = r * 256 + srcslot * 16;
            const int p = bm * 256 + r;
            const int b = p / 3136, rem = p % 3136;
            const int hh = rem / 56, ww = rem % 56;
            pA[h][j] = xq + ((size_t)b * 3364 + (size_t)(hh + 1) * 58 + (ww + 1)) * 256
                          + srcslot * 16;
        }

    // ---- frag read byte offsets (within each 256x128B region) ----
    const int slot0 = ((kseg)     ^ (lr & 7)) * 16;    // k64-half 0
    const int slot1 = ((4 + kseg) ^ (lr & 7)) * 16;    // k64-half 1
    const int aB = ((wave >> 2) * 128 + lr) * 128;
    const int bB = ((wave & 3) * 64 + lr) * 128;
    const int aK0 = aB + slot0, aK1 = aB + slot1;
    const int bK0 = bB + slot0, bK1 = bB + slot1;

    i32x4 acc[8][4];
    #pragma unroll
    for (int f = 0; f < 8; ++f)
        #pragma unroll
        for (int n = 0; n < 4; ++n)
            acc[f][n] = (i32x4){0, 0, 0, 0};

    // ---- prologue: B0[0]h0,h1; A0[0]h0,h1; B1[1]h0,h1; A1[1]h0 (7 stages, 14 issues) ----
    stageB(wbt, bOf[0][0], bOf[0][1], &lds[SB0 + dOf[0][0]], &lds[SB0 + dOf[0][1]], 0);
    stageB(wbt, bOf[1][0], bOf[1][1], &lds[SB0 + dOf[1][0]], &lds[SB0 + dOf[1][1]], 0);
    stageA(pA[0][0], pA[0][1], &lds[SA0 + dOf[0][0]], &lds[SA0 + dOf[0][1]], 0);
    stageA(pA[1][0], pA[1][1], &lds[SA0 + dOf[1][0]], &lds[SA0 + dOf[1][1]], 0);
    stageB(wbt, bOf[0][0], bOf[0][1], &lds[SB1 + dOf[0][0]], &lds[SB1 + dOf[0][1]], 1);
    stageB(wbt, bOf[1][0], bOf[1][1], &lds[SB1 + dOf[1][0]], &lds[SB1 + dOf[1][1]], 1);
    stageA(pA[0][0], pA[0][1], &lds[SA1 + dOf[0][0]], &lds[SA1 + dOf[0][1]], 1);
    asm volatile("s_waitcnt vmcnt(8)" ::: "memory");
    BAR();

    i32x4 bk0[4], bk1[4];

    // 9 iterations; iteration i = tap i, two K=128 steps (even buf / odd buf)
    for (int i = 0; i < 9; ++i) {
        const bool last = (i == 8);
        const int te = 2 * i + 2;
        const int to = 2 * i + 3;

        // ===== ph1: A(buf0,fh0,k0) + all B(buf0); stage A1h1[2i+1] =====
        {
            i32x4 af[4];
            #pragma unroll
            for (int f = 0; f < 4; ++f) af[f] = *(const i32x4*)&lds[SA0 + aK0 + f * 2048];
            #pragma unroll
            for (int n = 0; n < 4; ++n) {
                bk0[n] = *(const i32x4*)&lds[SB0 + bK0 + n * 2048];
                bk1[n] = *(const i32x4*)&lds[SB0 + bK1 + n * 2048];
            }
            stageA(pA[1][0], pA[1][1], &lds[SA1 + dOf[1][0]], &lds[SA1 + dOf[1][1]], 2 * i + 1);
            BAR();
            __builtin_amdgcn_s_setprio(1);
            #pragma unroll
            for (int f = 0; f < 4; ++f)
                #pragma unroll
                for (int n = 0; n < 4; ++n) mfma_i8(acc[f][n], af[f], bk0[n]);
            __builtin_amdgcn_s_setprio(0);
            BAR();
        }
        // ===== ph2: A(buf0,fh0,k1); stage B0h0[te]; vmcnt =====
        {
            i32x4 af[4];
            #pragma unroll
            for (int f = 0; f < 4; ++f) af[f] = *(const i32x4*)&lds[SA0 + aK1 + f * 2048];
            if (!last) {
                stageB(wbt, bOf[0][0], bOf[0][1], &lds[SB0 + dOf[0][0]], &lds[SB0 + dOf[0][1]], te);
                asm volatile("s_waitcnt vmcnt(10)" ::: "memory");
            } else {
                asm volatile("s_waitcnt vmcnt(8)" ::: "memory");
            }
            BAR();
            __builtin_amdgcn_s_setprio(1);
            #pragma unroll
            for (int f = 0; f < 4; ++f)
                #pragma unroll
                for (int n = 0; n < 4; ++n) mfma_i8(acc[f][n], af[f], bk1[n]);
            __builtin_amdgcn_s_setprio(0);
            BAR();
        }
        // ===== ph3: A(buf0,fh1,k0); stage B0h1[te] =====
        {
            i32x4 af[4];
            #pragma unroll
            for (int f = 0; f < 4; ++f) af[f] = *(const i32x4*)&lds[SA0 + aK0 + (f + 4) * 2048];
            if (!last) stageB(wbt, bOf[1][0], bOf[1][1], &lds[SB0 + dOf[1][0]], &lds[SB0 + dOf[1][1]], te);
            BAR();
            __builtin_amdgcn_s_setprio(1);
            #pragma unroll
            for (int f = 0; f < 4; ++f)
                #pragma unroll
                for (int n = 0; n < 4; ++n) mfma_i8(acc[f + 4][n], af[f], bk0[n]);
            __builtin_amdgcn_s_setprio(0);
            BAR();
        }
        // ===== ph4: A(buf0,fh1,k1); stage A0h0[te]; vmcnt =====
        {
            i32x4 af[4];
            #pragma unroll
            for (int f = 0; f < 4; ++f) af[f] = *(const i32x4*)&lds[SA0 + aK1 + (f + 4) * 2048];
            if (!last) {
                stageA(pA[0][0], pA[0][1], &lds[SA0 + dOf[0][0]], &lds[SA0 + dOf[0][1]], te);
                asm volatile("s_waitcnt vmcnt(8)" ::: "memory");
            } else {
                asm volatile("s_waitcnt vmcnt(2)" ::: "memory");
            }
            BAR();
            __builtin_amdgcn_s_setprio(1);
            #pragma unroll
            for (int f = 0; f < 4; ++f)
                #pragma unroll
                for (int n = 0; n < 4; ++n) mfma_i8(acc[f + 4][n], af[f], bk1[n]);
            __builtin_amdgcn_s_setprio(0);
            BAR();
        }
        // ===== ph5: A(buf1,fh0,k0) + all B(buf1); stage A0h1[te] (src pA[1]!) =====
        {
            i32x4 af[4];
            #pragma unroll
            for (int f = 0; f < 4; ++f) af[f] = *(const i32x4*)&lds[SA1 + aK0 + f * 2048];
            #pragma unroll
            for (int n = 0; n < 4; ++n) {
                bk0[n] = *(const i32x4*)&lds[SB1 + bK0 + n * 2048];
                bk1[n] = *(const i32x4*)&lds[SB1 + bK1 + n * 2048];
            }
            if (!last) stageA(pA[1][0], pA[1][1], &lds[SA0 + dOf[1][0]], &lds[SA0 + dOf[1][1]], te);
            BAR();
            __builtin_amdgcn_s_setprio(1);
            #pragma unroll
            for (int f = 0; f < 4; ++f)
                #pragma unroll
                for (int n = 0; n < 4; ++n) mfma_i8(acc[f][n], af[f], bk0[n]);
            __builtin_amdgcn_s_setprio(0);
            BAR();
        }
        // ===== ph6: A(buf1,fh0,k1); stage B1h0[to]; vmcnt =====
        {
            i32x4 af[4];
            #pragma unroll
            for (int f = 0; f < 4; ++f) af[f] = *(const i32x4*)&lds[SA1 + aK1 + f * 2048];
            if (!last) {
                stageB(wbt, bOf[0][0], bOf[0][1], &lds[SB1 + dOf[0][0]], &lds[SB1 + dOf[0][1]], to);
                asm volatile("s_waitcnt vmcnt(10)" ::: "memory");
            } else {
                asm volatile("s_waitcnt vmcnt(0)" ::: "memory");
            }
            BAR();
            __builtin_amdgcn_s_setprio(1);
            #pragma unroll
            for (int f = 0; f < 4; ++f)
                #pragma unroll
                for (int n = 0; n < 4; ++n) mfma_i8(acc[f][n], af[f], bk1[n]);
            __builtin_amdgcn_s_setprio(0);
            BAR();
        }
        // ===== ph7: A(buf1,fh1,k0); stage B1h1[to] =====
        {
            i32x4 af[4];
            #pragma unroll
            for (int f = 0; f < 4; ++f) af[f] = *(const i32x4*)&lds[SA1 + aK0 + (f + 4) * 2048];
            if (!last) stageB(wbt, bOf[1][0], bOf[1][1], &lds[SB1 + dOf[1][0]], &lds[SB1 + dOf[1][1]], to);
            BAR();
            __builtin_amdgcn_s_setprio(1);
            #pragma unroll
            for (int f = 0; f < 4; ++f)
                #pragma unroll
                for (int n = 0; n < 4; ++n) mfma_i8(acc[f + 4][n], af[f], bk0[n]);
            __builtin_amdgcn_s_setprio(0);
            BAR();
        }
        // ===== ph8: A(buf1,fh1,k1); stage A1h0[to] (src pA[0]!); vmcnt =====
        {
            i32x4 af[4];
            #pragma unroll
            for (int f = 0; f < 4; ++f) af[f] = *(const i32x4*)&lds[SA1 + aK1 + (f + 4) * 2048];
            if (!last) {
                stageA(pA[0][0], pA[0][1], &lds[SA1 + dOf[0][0]], &lds[SA1 + dOf[0][1]], to);
                asm volatile("s_waitcnt vmcnt(8)" ::: "memory");
            }
            BAR();
            __builtin_amdgcn_s_setprio(1);
            #pragma unroll
            for (int f = 0; f < 4; ++f)
                #pragma unroll
                for (int n = 0; n < 4; ++n) mfma_i8(acc[f + 4][n], af[f], bk1[n]);
            __builtin_amdgcn_s_setprio(0);
            BAR();
        }
    }

    // ---- epilogue: C/D map col=lane&15, row=(lane>>4)*4+j; dequant ----
    const int row0 = bm * 256 + (wave >> 2) * 128 + (lane >> 4) * 4;
    const int col0 = (wave & 3) * 64 + lr;
    #pragma unroll
    for (int f = 0; f < 8; ++f)
        #pragma unroll
        for (int n = 0; n < 4; ++n) {
            const int r = row0 + f * 16;
            const int c = col0 + n * 16;
            #pragma unroll
            for (int j = 0; j < 4; ++j)
                out[(size_t)(r + j) * COUT + c] = QDEQ * (float)acc[f][n][j];
        }
}

// =====================  fallback (tiny ws): bf16 reg-staged  =====================
__global__ void binw_bf16(const float* __restrict__ w, __bf16* __restrict__ wbt) {
    const int cout = threadIdx.x;
    const int rc   = blockIdx.x;
    const float v  = w[(size_t)rc * COUT + cout];
    const float s  = (v > 0.f) ? 1.f : ((v < 0.f) ? -1.f : 0.f);
    wbt[((size_t)((rc >> 8) * COUT + cout)) * CIN + (rc & 255)] = (__bf16)s;
}

__global__ __launch_bounds__(512) void conv_fb(const float* __restrict__ x,
                                               const __bf16* __restrict__ wbt,
                                               float* __restrict__ out) {
    __shared__ __bf16 Alds[128][72];
    __shared__ __bf16 Blds[256][72];
    typedef __bf16 bf8 __attribute__((ext_vector_type(8)));

    const int tid  = threadIdx.x;
    const int lane = tid & 63;
    const int wave = tid >> 6;
    const int m_base = (wave >> 2) * 64;
    const int n_base = (wave & 3) * 64;
    const int lr = lane & 15;
    const int kb = (lane >> 4) * 8;

    const int arow = tid >> 2;
    const int aseg = tid & 3;
    const int p    = blockIdx.x * 128 + arow;
    const int rem  = p % 3136;
    const int h    = rem / 56;
    const int wc   = rem % 56;

    f32x4 acc[4][4];
    #pragma unroll
    for (int i = 0; i < 4; ++i)
        #pragma unroll
        for (int j = 0; j < 4; ++j)
            acc[i][j] = (f32x4){0.f, 0.f, 0.f, 0.f};

    for (int tap = 0; tap < 9; ++tap) {
        const int dh = tap / 3 - 1;
        const int dw = tap % 3 - 1;
        const bool valid = ((unsigned)(h + dh) < 56u) && ((unsigned)(wc + dw) < 56u);
        const long aoff = ((long)p + (long)dh * 56 + dw) * CIN + aseg * 16;
        const __bf16* bsrc = wbt + (size_t)tap * COUT * CIN;

        #pragma unroll
        for (int ks = 0; ks < 4; ++ks) {
            const int c0 = ks * 64;
            __syncthreads();
            f32x4 f0, f1, f2, f3;
            if (valid) {
                const f32x4* s4 = (const f32x4*)(x + aoff + c0);
                f0 = s4[0]; f1 = s4[1]; f2 = s4[2]; f3 = s4[3];
            } else {
                f0 = f1 = f2 = f3 = (f32x4){0.f, 0.f, 0.f, 0.f};
            }
            bf8 v0, v1;
            #pragma unroll
            for (int j = 0; j < 4; ++j) {
                v0[j] = (__bf16)f0[j]; v0[j + 4] = (__bf16)f1[j];
                v1[j] = (__bf16)f2[j]; v1[j + 4] = (__bf16)f3[j];
            }
            *(bf8*)&Alds[arow][aseg * 16]     = v0;
            *(bf8*)&Alds[arow][aseg * 16 + 8] = v1;
            #pragma unroll
            for (int i = 0; i < 4; ++i) {
                const int chunk = tid + i * 512;
                const int row = chunk >> 3;
                const int cs  = chunk & 7;
                *(uint4*)&Blds[row][cs * 8] = *(const uint4*)(bsrc + row * CIN + c0 + cs * 8);
            }
            __syncthreads();

            bf8 af[4][2], bfr[4][2];
            #pragma unroll
            for (int mf = 0; mf < 4; ++mf)
                #pragma unroll
                for (int kf = 0; kf < 2; ++kf)
                    af[mf][kf] = *(const bf8*)&Alds[m_base + mf * 16 + lr][kf * 32 + kb];
            #pragma unroll
            for (int nf = 0; nf < 4; ++nf)
                #pragma unroll
                for (int kf = 0; kf < 2; ++kf)
                    bfr[nf][kf] = *(const bf8*)&Blds[n_base + nf * 16 + lr][kf * 32 + kb];
            #pragma unroll
            for (int kf = 0; kf < 2; ++kf)
                #pragma unroll
                for (int mf = 0; mf < 4; ++mf)
                    #pragma unroll
                    for (int nf = 0; nf < 4; ++nf)
                        acc[mf][nf] = __builtin_amdgcn_mfma_f32_16x16x32_bf16(
                            af[mf][kf], bfr[nf][kf], acc[mf][nf], 0, 0, 0);
        }
    }
    #pragma unroll
    for (int mf = 0; mf < 4; ++mf)
        #pragma unroll
        for (int nf = 0; nf < 4; ++nf) {
            const int r0 = blockIdx.x * 128 + m_base + mf * 16 + (lane >> 4) * 4;
            const int c  = n_base + nf * 16 + lr;
            #pragma unroll
            for (int j = 0; j < 4; ++j)
                out[(size_t)(r0 + j) * COUT + c] = acc[mf][nf][j];
        }
}

extern "C" void kernel_launch(void* const* d_in, const int* in_sizes, int n_in,
                              void* d_out, int out_size, void* d_ws, size_t ws_size,
                              hipStream_t stream) {
    const float* x = (const float*)d_in[0];
    const float* w = (const float*)d_in[1];
    float* out = (float*)d_out;
    char* ws = (char*)d_ws;

    if (ws_size >= WS_NEED_I8) {
        signed char* wbt = (signed char*)(ws + WBT_OFF);
        signed char* xq  = (signed char*)(ws + XQ_OFF);
        binw_i8<<<9 * CIN, COUT, 0, stream>>>(w, wbt);
        xq_kernel<<<13456, 256, 0, stream>>>(x, xq);
        conv8i<<<392, 512, 0, stream>>>(xq, wbt, out);
    } else {
        __bf16* wbt = (__bf16*)(ws + WBT_OFF);
        binw_bf16<<<9 * CIN, COUT, 0, stream>>>(w, wbt);
        conv_fb<<<NPIX / 128, 512, 0, stream>>>(x, wbt, out);
    }
}

// Round 6
// 89.796 us; speedup vs baseline: 2.9430x; 1.0828x over previous
//
#include <hip/hip_runtime.h>
#include <hip/hip_bf16.h>

typedef int    i32x4 __attribute__((ext_vector_type(4)));
typedef float  f32x4 __attribute__((ext_vector_type(4)));

#define NPIX  100352   // 32*56*56
#define CIN   256
#define COUT  256

#define QC    4.75f
#define QINV  (127.0f/QC)
#define QDEQ  (QC/127.0f)

#define WBT_OFF 0u
#define XQ_OFF  (1024u*1024u)
#define WS_NEED_I8 ((size_t)XQ_OFF + (size_t)32*3364*256)   // ~28.6 MB

#define BAR() do { asm volatile("" ::: "memory"); __builtin_amdgcn_s_barrier(); asm volatile("" ::: "memory"); } while(0)

// ---- merged prepass: blocks [0,13456) quantize+pad x; blocks [13456,15760) binarize w ----
__global__ __launch_bounds__(256) void prep_kernel(const float* __restrict__ x,
                                                   signed char* __restrict__ xq,
                                                   const float* __restrict__ w,
                                                   signed char* __restrict__ wbt) {
    const int bid = blockIdx.x;
    if (bid < 13456) {
        const int g = bid * 256 + threadIdx.x;          // chunk of 8 channels
        const int prow = g >> 5, cseg = g & 31;
        const int b = prow / 3364, rr = prow % 3364;
        const int ph = rr / 58, pw = rr % 58;
        int2 pack = {0, 0};
        if (ph >= 1 && ph <= 56 && pw >= 1 && pw <= 56) {
            const size_t s = ((size_t)b * 3136 + (size_t)(ph - 1) * 56 + (pw - 1)) * 256 + cseg * 8;
            const f32x4 a = *(const f32x4*)(x + s);
            const f32x4 c = *(const f32x4*)(x + s + 4);
            unsigned lo = 0, hi = 0;
            #pragma unroll
            for (int j = 0; j < 4; ++j) {
                int qa = (int)rintf(fminf(fmaxf(a[j], -QC), QC) * QINV);
                int qc = (int)rintf(fminf(fmaxf(c[j], -QC), QC) * QINV);
                lo |= (unsigned)(qa & 255) << (8 * j);
                hi |= (unsigned)(qc & 255) << (8 * j);
            }
            pack.x = (int)lo; pack.y = (int)hi;
        }
        *(int2*)(xq + (size_t)g * 8) = pack;
    } else {
        const int rc   = bid - 13456;                   // tap*256 + cin
        const int cout = threadIdx.x;
        const float v  = w[(size_t)rc * COUT + cout];
        const signed char s = (v > 0.f) ? 1 : ((v < 0.f) ? -1 : 0);
        const int tap = rc >> 8;
        const int cin = rc & 255;
        wbt[((size_t)(tap * COUT + cout)) * CIN + cin] = s;
    }
}

__device__ __forceinline__ void gll16(const signed char* g, signed char* l) {
    __builtin_amdgcn_global_load_lds(
        (const __attribute__((address_space(1))) void*)g,
        (__attribute__((address_space(3))) void*)l, 16, 0, 0);
}

__device__ __forceinline__ void mfma_i8(i32x4& acc, i32x4 a, i32x4 b) {
    asm("v_mfma_i32_16x16x64_i8 %0, %1, %2, %0" : "+v"(acc) : "v"(a), "v"(b));
}

// =====================  4-phase 128x128 i8 kernel, BK=128, 2 blocks/CU  =====================
// LDS byte offsets: A0,B0,A1,B1 each 128 rows x 128 B = 16 KB (total 64 KB)
#define SA0 0
#define SB0 16384
#define SA1 32768
#define SB1 49152

#define STAGE_A(REG, TS) do {                                                        \
    const int tap_ = (TS) >> 1;                                                      \
    const int dh1_ = (tap_ * 11) >> 5;  /* tap/3 */                                  \
    const int off_ = ((dh1_ - 1) * 58 + (tap_ - dh1_ * 3 - 1)) * 256 + (((TS) & 1) << 7); \
    _Pragma("unroll")                                                                \
    for (int j_ = 0; j_ < 4; ++j_) gll16(pA[j_] + off_, &lds[(REG) + dOf[j_]]);      \
} while (0)

#define STAGE_B(REG, TS) do {                                                        \
    const signed char* s_ = wbt + (((TS) >> 1) << 16) + (((TS) & 1) << 7);           \
    _Pragma("unroll")                                                                \
    for (int j_ = 0; j_ < 4; ++j_) gll16(s_ + bOf[j_], &lds[(REG) + dOf[j_]]);       \
} while (0)

__global__ __launch_bounds__(256, 2) void conv4i(const signed char* __restrict__ xq,
                                                 const signed char* __restrict__ wbt,
                                                 float* __restrict__ out) {
    __shared__ signed char lds[65536];

    const int tid  = threadIdx.x;
    const int lane = tid & 63;
    const int wave = tid >> 6;                  // 0..3
    const int l3 = lane >> 3, l7 = lane & 7;
    const int srcslot = l7 ^ l3;                // source swizzle involution (8 slots x 16B)
    const int lr = lane & 15, kseg = lane >> 4;

    // 1568 blocks = 8 XCD chunks x 196; chunked bijective swizzle
    const int bid = blockIdx.x;
    const int L   = (bid & 7) * 196 + (bid >> 3);
    const int bm  = L >> 1;                     // 0..783 (128-pixel tile)
    const int bn  = L & 1;                      // 0..1   (128-cout tile)

    // ---- staging geometry: wave w owns rows w*32..w*32+31, 4 issues of 8 rows ----
    const signed char* pA[4];
    int bOf[4], dOf[4];
    #pragma unroll
    for (int j = 0; j < 4; ++j) {
        const int rb = wave * 32 + j * 8;
        dOf[j] = rb * 128;                      // wave-uniform LDS byte offset
        const int r = rb + l3;                  // per-lane row
        bOf[j] = (bn * 128 + r) * 256 + srcslot * 16;
        const int p = bm * 128 + r;
        const int b = p / 3136, rem = p % 3136;
        const int hh = rem / 56, ww = rem % 56;
        pA[j] = xq + ((size_t)b * 3364 + (size_t)(hh + 1) * 58 + (ww + 1)) * 256
                   + srcslot * 16;
    }

    // ---- frag read byte offsets ----
    const int m_base = (wave >> 1) * 64;
    const int n_base = (wave & 1) * 64;
    const int slot0 = ((kseg)     ^ (lr & 7)) * 16;
    const int slot1 = ((4 + kseg) ^ (lr & 7)) * 16;
    const int aB = (m_base + lr) * 128;
    const int bB = (n_base + lr) * 128;
    const int aK0 = aB + slot0, aK1 = aB + slot1;
    const int bK0 = bB + slot0, bK1 = bB + slot1;

    i32x4 acc[4][4];
    #pragma unroll
    for (int f = 0; f < 4; ++f)
        #pragma unroll
        for (int n = 0; n < 4; ++n)
            acc[f][n] = (i32x4){0, 0, 0, 0};

    // ---- prologue: B0(0), A0(0), B1(1) = 12 issues; drain t0 ----
    STAGE_B(SB0, 0);
    STAGE_A(SA0, 0);
    STAGE_B(SB1, 1);
    asm volatile("s_waitcnt vmcnt(4)" ::: "memory");
    BAR();

    i32x4 bk0[4], bk1[4];

    // 9 iterations; iter i = steps 2i (buf0) and 2i+1 (buf1)
    for (int i = 0; i < 9; ++i) {
        const bool last = (i == 8);
        const int te = 2 * i + 2;
        const int to = 2 * i + 3;

        // ===== ph1: A(buf0,k0) + all B(buf0); stage A1(2i+1) =====
        {
            i32x4 af[4];
            #pragma unroll
            for (int f = 0; f < 4; ++f) af[f] = *(const i32x4*)&lds[SA0 + aK0 + f * 2048];
            #pragma unroll
            for (int n = 0; n < 4; ++n) {
                bk0[n] = *(const i32x4*)&lds[SB0 + bK0 + n * 2048];
                bk1[n] = *(const i32x4*)&lds[SB0 + bK1 + n * 2048];
            }
            STAGE_A(SA1, 2 * i + 1);
            BAR();
            __builtin_amdgcn_s_setprio(1);
            #pragma unroll
            for (int f = 0; f < 4; ++f)
                #pragma unroll
                for (int n = 0; n < 4; ++n) mfma_i8(acc[f][n], af[f], bk0[n]);
            __builtin_amdgcn_s_setprio(0);
            BAR();
        }
        // ===== ph2: A(buf0,k1); stage B0(te); vmcnt =====
        {
            i32x4 af[4];
            #pragma unroll
            for (int f = 0; f < 4; ++f) af[f] = *(const i32x4*)&lds[SA0 + aK1 + f * 2048];
            if (!last) {
                STAGE_B(SB0, te);
                asm volatile("s_waitcnt vmcnt(4)" ::: "memory");
            } else {
                asm volatile("s_waitcnt vmcnt(0)" ::: "memory");
            }
            BAR();
            __builtin_amdgcn_s_setprio(1);
            #pragma unroll
            for (int f = 0; f < 4; ++f)
                #pragma unroll
                for (int n = 0; n < 4; ++n) mfma_i8(acc[f][n], af[f], bk1[n]);
            __builtin_amdgcn_s_setprio(0);
            BAR();
        }
        // ===== ph3: A(buf1,k0) + all B(buf1); stage A0(te) =====
        {
            i32x4 af[4];
            #pragma unroll
            for (int f = 0; f < 4; ++f) af[f] = *(const i32x4*)&lds[SA1 + aK0 + f * 2048];
            #pragma unroll
            for (int n = 0; n < 4; ++n) {
                bk0[n] = *(const i32x4*)&lds[SB1 + bK0 + n * 2048];
                bk1[n] = *(const i32x4*)&lds[SB1 + bK1 + n * 2048];
            }
            if (!last) STAGE_A(SA0, te);
            BAR();
            __builtin_amdgcn_s_setprio(1);
            #pragma unroll
            for (int f = 0; f < 4; ++f)
                #pragma unroll
                for (int n = 0; n < 4; ++n) mfma_i8(acc[f][n], af[f], bk0[n]);
            __builtin_amdgcn_s_setprio(0);
            BAR();
        }
        // ===== ph4: A(buf1,k1); stage B1(to); vmcnt =====
        {
            i32x4 af[4];
            #pragma unroll
            for (int f = 0; f < 4; ++f) af[f] = *(const i32x4*)&lds[SA1 + aK1 + f * 2048];
            if (!last) {
                STAGE_B(SB1, to);
                asm volatile("s_waitcnt vmcnt(4)" ::: "memory");
            }
            BAR();
            __builtin_amdgcn_s_setprio(1);
            #pragma unroll
            for (int f = 0; f < 4; ++f)
                #pragma unroll
                for (int n = 0; n < 4; ++n) mfma_i8(acc[f][n], af[f], bk1[n]);
            __builtin_amdgcn_s_setprio(0);
            BAR();
        }
    }

    // ---- epilogue: C/D map col=lane&15, row=(lane>>4)*4+j; dequant ----
    const int row0 = bm * 128 + m_base + (lane >> 4) * 4;
    const int col0 = bn * 128 + n_base + lr;
    #pragma unroll
    for (int f = 0; f < 4; ++f)
        #pragma unroll
        for (int n = 0; n < 4; ++n) {
            const int r = row0 + f * 16;
            const int c = col0 + n * 16;
            #pragma unroll
            for (int j = 0; j < 4; ++j)
                out[(size_t)(r + j) * COUT + c] = QDEQ * (float)acc[f][n][j];
        }
}

// =====================  fallback (tiny ws): bf16 reg-staged  =====================
__global__ void binw_bf16(const float* __restrict__ w, __bf16* __restrict__ wbt) {
    const int cout = threadIdx.x;
    const int rc   = blockIdx.x;
    const float v  = w[(size_t)rc * COUT + cout];
    const float s  = (v > 0.f) ? 1.f : ((v < 0.f) ? -1.f : 0.f);
    wbt[((size_t)((rc >> 8) * COUT + cout)) * CIN + (rc & 255)] = (__bf16)s;
}

__global__ __launch_bounds__(512) void conv_fb(const float* __restrict__ x,
                                               const __bf16* __restrict__ wbt,
                                               float* __restrict__ out) {
    __shared__ __bf16 Alds[128][72];
    __shared__ __bf16 Blds[256][72];
    typedef __bf16 bf8 __attribute__((ext_vector_type(8)));

    const int tid  = threadIdx.x;
    const int lane = tid & 63;
    const int wave = tid >> 6;
    const int m_base = (wave >> 2) * 64;
    const int n_base = (wave & 3) * 64;
    const int lr = lane & 15;
    const int kb = (lane >> 4) * 8;

    const int arow = tid >> 2;
    const int aseg = tid & 3;
    const int p    = blockIdx.x * 128 + arow;
    const int rem  = p % 3136;
    const int h    = rem / 56;
    const int wc   = rem % 56;

    f32x4 acc[4][4];
    #pragma unroll
    for (int i = 0; i < 4; ++i)
        #pragma unroll
        for (int j = 0; j < 4; ++j)
            acc[i][j] = (f32x4){0.f, 0.f, 0.f, 0.f};

    for (int tap = 0; tap < 9; ++tap) {
        const int dh = tap / 3 - 1;
        const int dw = tap % 3 - 1;
        const bool valid = ((unsigned)(h + dh) < 56u) && ((unsigned)(wc + dw) < 56u);
        const long aoff = ((long)p + (long)dh * 56 + dw) * CIN + aseg * 16;
        const __bf16* bsrc = wbt + (size_t)tap * COUT * CIN;

        #pragma unroll
        for (int ks = 0; ks < 4; ++ks) {
            const int c0 = ks * 64;
            __syncthreads();
            f32x4 f0, f1, f2, f3;
            if (valid) {
                const f32x4* s4 = (const f32x4*)(x + aoff + c0);
                f0 = s4[0]; f1 = s4[1]; f2 = s4[2]; f3 = s4[3];
            } else {
                f0 = f1 = f2 = f3 = (f32x4){0.f, 0.f, 0.f, 0.f};
            }
            bf8 v0, v1;
            #pragma unroll
            for (int j = 0; j < 4; ++j) {
                v0[j] = (__bf16)f0[j]; v0[j + 4] = (__bf16)f1[j];
                v1[j] = (__bf16)f2[j]; v1[j + 4] = (__bf16)f3[j];
            }
            *(bf8*)&Alds[arow][aseg * 16]     = v0;
            *(bf8*)&Alds[arow][aseg * 16 + 8] = v1;
            #pragma unroll
            for (int i = 0; i < 4; ++i) {
                const int chunk = tid + i * 512;
                const int row = chunk >> 3;
                const int cs  = chunk & 7;
                *(uint4*)&Blds[row][cs * 8] = *(const uint4*)(bsrc + row * CIN + c0 + cs * 8);
            }
            __syncthreads();

            bf8 af[4][2], bfr[4][2];
            #pragma unroll
            for (int mf = 0; mf < 4; ++mf)
                #pragma unroll
                for (int kf = 0; kf < 2; ++kf)
                    af[mf][kf] = *(const bf8*)&Alds[m_base + mf * 16 + lr][kf * 32 + kb];
            #pragma unroll
            for (int nf = 0; nf < 4; ++nf)
                #pragma unroll
                for (int kf = 0; kf < 2; ++kf)
                    bfr[nf][kf] = *(const bf8*)&Blds[n_base + nf * 16 + lr][kf * 32 + kb];
            #pragma unroll
            for (int kf = 0; kf < 2; ++kf)
                #pragma unroll
                for (int mf = 0; mf < 4; ++mf)
                    #pragma unroll
                    for (int nf = 0; nf < 4; ++nf)
                        acc[mf][nf] = __builtin_amdgcn_mfma_f32_16x16x32_bf16(
                            af[mf][kf], bfr[nf][kf], acc[mf][nf], 0, 0, 0);
        }
    }
    #pragma unroll
    for (int mf = 0; mf < 4; ++mf)
        #pragma unroll
        for (int nf = 0; nf < 4; ++nf) {
            const int r0 = blockIdx.x * 128 + m_base + mf * 16 + (lane >> 4) * 4;
            const int c  = n_base + nf * 16 + lr;
            #pragma unroll
            for (int j = 0; j < 4; ++j)
                out[(size_t)(r0 + j) * COUT + c] = acc[mf][nf][j];
        }
}

extern "C" void kernel_launch(void* const* d_in, const int* in_sizes, int n_in,
                              void* d_out, int out_size, void* d_ws, size_t ws_size,
                              hipStream_t stream) {
    const float* x = (const float*)d_in[0];
    const float* w = (const float*)d_in[1];
    float* out = (float*)d_out;
    char* ws = (char*)d_ws;

    if (ws_size >= WS_NEED_I8) {
        signed char* wbt = (signed char*)(ws + WBT_OFF);
        signed char* xq  = (signed char*)(ws + XQ_OFF);
        prep_kernel<<<13456 + 2304, 256, 0, stream>>>(x, xq, w, wbt);
        conv4i<<<1568, 256, 0, stream>>>(xq, wbt, out);
    } else {
        __bf16* wbt = (__bf16*)(ws + WBT_OFF);
        binw_bf16<<<9 * CIN, COUT, 0, stream>>>(w, wbt);
        conv_fb<<<NPIX / 128, 512, 0, stream>>>(x, wbt, out);
    }
}